// Round 7
// baseline (790.132 us; speedup 1.0000x reference)
//
#include <hip/hip_runtime.h>
#include <hip/hip_bf16.h>
#include <cstdint>

#define HD 256
#define NHEADS 8
#define NB 256
#define SL 64
#define NN 16384
#define NE 131072
#define NTOT (NE + NN)   // 147456

typedef float floatx4 __attribute__((ext_vector_type(4)));
typedef short shortx8 __attribute__((ext_vector_type(8)));
typedef unsigned short ushortx8 __attribute__((ext_vector_type(8)));
typedef unsigned short ushortx4 __attribute__((ext_vector_type(4)));
typedef unsigned uintx4 __attribute__((ext_vector_type(4)));

__device__ __forceinline__ unsigned short f2bf(float f) {
    union { float f; unsigned u; } a; a.f = f;
    unsigned r = a.u + 0x7fffu + ((a.u >> 16) & 1u);
    return (unsigned short)(r >> 16);
}
__device__ __forceinline__ float bf2f(unsigned short b) {
    union { unsigned u; float f; } a; a.u = ((unsigned)b) << 16;
    return a.f;
}

// system-coherent (write-through / L2-bypass) accessors for cross-block h exchange.
// sc0 sc1 => the access happens at the coherence point (L3/IC); L2 is never dirty
// and never serves stale lines, so no buffer_wbl2/buffer_inv walks are needed
// (v7's 13.6k cy/step cost) and no release/acquire fences either (v8 proved this).
__device__ __forceinline__ void store_b32_sys(unsigned* p, unsigned v) {
    asm volatile("global_store_dword %0, %1, off sc0 sc1" :: "v"(p), "v"(v) : "memory");
}
__device__ __forceinline__ uintx4 load_b128_sys_u(const unsigned* p) {
    uintx4 r;
    asm volatile("global_load_dwordx4 %0, %1, off sc0 sc1" : "=v"(r) : "v"(p) : "memory");
    return r;
}

// ---------------- conversions ----------------

__global__ void k_cast_bf16(const float* __restrict__ in, unsigned short* __restrict__ out, int n4) {
    int i = blockIdx.x * 256 + threadIdx.x;
    if (i >= n4) return;
    float4 v = ((const float4*)in)[i];
    ushortx4 o;
    o[0] = f2bf(v.x); o[1] = f2bf(v.y); o[2] = f2bf(v.z); o[3] = f2bf(v.w);
    *(ushortx4*)&out[i * 4] = o;
}

// out[n][k] = bf16(in[k][n]); in is K x N fp32. grid (N/32, K/32), block (32,8)
__global__ void k_transpose_bf16(const float* __restrict__ in, unsigned short* __restrict__ out,
                                 int K, int N) {
    __shared__ float t[32][33];
    int nb = blockIdx.x * 32, kb = blockIdx.y * 32;
    int tx = threadIdx.x, ty = threadIdx.y;
#pragma unroll
    for (int i = 0; i < 4; ++i) {
        int k = kb + ty + i * 8;
        t[ty + i * 8][tx] = in[(size_t)k * N + nb + tx];
    }
    __syncthreads();
#pragma unroll
    for (int i = 0; i < 4; ++i) {
        int nrow = nb + ty + i * 8;
        out[(size_t)nrow * K + kb + tx] = f2bf(t[tx][ty + i * 8]);
    }
}

__global__ void k_add2(const float* __restrict__ a, const float* __restrict__ b,
                       float* __restrict__ o, int n) {
    int i = blockIdx.x * 256 + threadIdx.x;
    if (i < n) o[i] = a[i] + b[i];
}

__global__ void k_zero(int* __restrict__ p, int n) {
    int i = blockIdx.x * 256 + threadIdx.x;
    if (i < n) p[i] = 0;
}

// x_b[n][d] = bf16(emb[x_ids[n]][d]), row 0 of emb forced to 0
__global__ void k_gather_x(const int* __restrict__ ids, const float* __restrict__ emb,
                           unsigned short* __restrict__ xb) {
    int i = blockIdx.x * 256 + threadIdx.x;   // over NN*64
    int n = i >> 6, d4 = (i & 63) << 2;
    int id = ids[n];
    float4 v = make_float4(0.f, 0.f, 0.f, 0.f);
    if (id != 0) v = *(const float4*)&emb[(size_t)id * HD + d4];
    ushortx4 o;
    o[0] = f2bf(v.x); o[1] = f2bf(v.y); o[2] = f2bf(v.z); o[3] = f2bf(v.w);
    *(ushortx4*)&xb[(size_t)n * HD + d4] = o;
}

// ---------------- GEMM: C(MxN) = A(MxK bf16) * B^T  (B given as N x K bf16) ----------------

template <bool OUT_BF16, bool HAS_BIAS>
__global__ __launch_bounds__(256, 2) void k_gemm_bt(
    const unsigned short* __restrict__ A, const unsigned short* __restrict__ B,
    void* __restrict__ C, const float* __restrict__ bias, int M, int Nn, int K) {
    constexpr int LDT = 56;
    __shared__ unsigned short As[128 * LDT];
    __shared__ unsigned short Bs[128 * LDT];
    int tid = threadIdx.x;
    int wave = tid >> 6, lane = tid & 63;
    int q = lane >> 4, c16 = lane & 15;
    long m0 = (long)blockIdx.x * 128;
    long n0 = (long)blockIdx.y * 128;
    int wm = (wave & 1) << 6, wn = (wave >> 1) << 6;
    floatx4 acc[4][4] = {};
    int lrow = tid >> 2;
    int lk = (tid & 3) << 3;
    const unsigned short* Arow0 = A + (m0 + lrow) * K + lk;
    const unsigned short* Arow1 = A + (m0 + 64 + lrow) * K + lk;
    long nb0 = n0 + lrow;      if (nb0 >= Nn) nb0 = Nn - 1;
    long nb1 = n0 + 64 + lrow; if (nb1 >= Nn) nb1 = Nn - 1;
    const unsigned short* Brow0 = B + nb0 * K + lk;
    const unsigned short* Brow1 = B + nb1 * K + lk;

    for (int k0 = 0; k0 < K; k0 += 32) {
        ushortx8 a0 = *(const ushortx8*)(Arow0 + k0);
        ushortx8 a1 = *(const ushortx8*)(Arow1 + k0);
        ushortx8 b0 = *(const ushortx8*)(Brow0 + k0);
        ushortx8 b1 = *(const ushortx8*)(Brow1 + k0);
        __syncthreads();
        *(ushortx8*)&As[lrow * LDT + lk] = a0;
        *(ushortx8*)&As[(64 + lrow) * LDT + lk] = a1;
        *(ushortx8*)&Bs[lrow * LDT + lk] = b0;
        *(ushortx8*)&Bs[(64 + lrow) * LDT + lk] = b1;
        __syncthreads();
        shortx8 af[4], bfr[4];
#pragma unroll
        for (int mt = 0; mt < 4; ++mt)
            af[mt] = *(const shortx8*)&As[(wm + mt * 16 + c16) * LDT + q * 8];
#pragma unroll
        for (int nt = 0; nt < 4; ++nt)
            bfr[nt] = *(const shortx8*)&Bs[(wn + nt * 16 + c16) * LDT + q * 8];
#pragma unroll
        for (int mt = 0; mt < 4; ++mt)
#pragma unroll
            for (int nt = 0; nt < 4; ++nt)
                acc[mt][nt] = __builtin_amdgcn_mfma_f32_16x16x32_bf16(af[mt], bfr[nt], acc[mt][nt], 0, 0, 0);
    }
#pragma unroll
    for (int mt = 0; mt < 4; ++mt) {
        long row_base = m0 + wm + mt * 16 + q * 4;
#pragma unroll
        for (int nt = 0; nt < 4; ++nt) {
            long col = n0 + wn + nt * 16 + c16;
            if (col >= Nn) continue;
            float bv = HAS_BIAS ? bias[col] : 0.0f;
#pragma unroll
            for (int r = 0; r < 4; ++r) {
                float v = acc[mt][nt][r] + bv;
                long idx = (row_base + r) * (long)Nn + col;
                if (OUT_BF16) ((unsigned short*)C)[idx] = f2bf(v);
                else          ((float*)C)[idx] = v;
            }
        }
    }
}

// ---------------- attention dots ----------------

__global__ void k_alpha1(const unsigned short* __restrict__ h1b, const float* __restrict__ asrc,
                         const float* __restrict__ adst, float* __restrict__ als,
                         float* __restrict__ ald) {
    int n = blockIdx.x, t = threadIdx.x;
    ushortx8 hv = *(const ushortx8*)&h1b[(size_t)n * 2048 + t * 8];
    float s = 0.f, d = 0.f;
#pragma unroll
    for (int j = 0; j < 8; ++j) {
        float f = bf2f(hv[j]);
        s += f * asrc[t * 8 + j];
        d += f * adst[t * 8 + j];
    }
    for (int o = 16; o; o >>= 1) { s += __shfl_down(s, o, 32); d += __shfl_down(d, o, 32); }
    if ((t & 31) == 0) { als[n * 8 + (t >> 5)] = s; ald[n * 8 + (t >> 5)] = d; }
}

__global__ void k_alpha2(const unsigned short* __restrict__ x2b, const float* __restrict__ asrc,
                         const float* __restrict__ adst, float* __restrict__ als,
                         float* __restrict__ ald) {
    int n = blockIdx.x, t = threadIdx.x;
    ushortx4 hv = *(const ushortx4*)&x2b[(size_t)n * 256 + t * 4];
    float s = 0.f, d = 0.f;
#pragma unroll
    for (int j = 0; j < 4; ++j) {
        float f = bf2f(hv[j]);
        s += f * asrc[t * 4 + j];
        d += f * adst[t * 4 + j];
    }
    for (int o = 32; o; o >>= 1) { s += __shfl_down(s, o, 64); d += __shfl_down(d, o, 64); }
    if (t == 0) { als[n] = s; ald[n] = d; }
}

// ---------------- CSR build ----------------

__global__ void k_deg_init(int* __restrict__ deg) {
    int i = blockIdx.x * 256 + threadIdx.x;
    if (i < NN) deg[i] = 1;
}
__global__ void k_deg_count(const int* __restrict__ ei, int* __restrict__ deg) {
    int e = blockIdx.x * 256 + threadIdx.x;
    if (e < NE) atomicAdd(&deg[ei[NE + e]], 1);
}
__global__ void k_scan(const int* __restrict__ deg, int* __restrict__ row_start,
                       int* __restrict__ cursor) {
    __shared__ int s[1024];
    int t = threadIdx.x;
    int base = t * 16;
    int loc[16]; int sum = 0;
#pragma unroll
    for (int i = 0; i < 16; ++i) { loc[i] = deg[base + i]; sum += loc[i]; }
    s[t] = sum;
    __syncthreads();
    for (int o = 1; o < 1024; o <<= 1) {
        int v = (t >= o) ? s[t - o] : 0;
        __syncthreads();
        s[t] += v;
        __syncthreads();
    }
    int ex = s[t] - sum;
#pragma unroll
    for (int i = 0; i < 16; ++i) {
        row_start[base + i] = ex;
        cursor[base + i] = ex;
        ex += loc[i];
    }
    if (t == 0) row_start[NN] = NTOT;
}
__global__ void k_fill(const int* __restrict__ ei, int* __restrict__ cursor,
                       int* __restrict__ csr_src) {
    int e = blockIdx.x * 256 + threadIdx.x;
    if (e >= NTOT) return;
    int s, d;
    if (e < NE) { s = ei[e]; d = ei[NE + e]; }
    else        { s = e - NE; d = s; }
    int p = atomicAdd(&cursor[d], 1);
    csr_src[p] = s;
}

// ---------------- GAT aggregation ----------------

__global__ __launch_bounds__(256) void k_agg1(
    const int* __restrict__ row_start, const int* __restrict__ csr_src,
    const float* __restrict__ als, const float* __restrict__ ald,
    const unsigned short* __restrict__ h1b, const float* __restrict__ b1,
    unsigned short* __restrict__ out1b) {
    int n = blockIdx.x, t = threadIdx.x;
    int rs = row_start[n];
    int deg = row_start[n + 1] - rs;
    __shared__ float sm[8], sz[8], sad[8];
    if (t < 8) sad[t] = ald[n * 8 + t];
    __syncthreads();
    int hh = t >> 5, ii = t & 31;
    float adh = sad[hh];
    float lm = -1e30f;
    for (int i = ii; i < deg; i += 32) {
        int s = csr_src[rs + i];
        float e = als[s * 8 + hh] + adh;
        e = e >= 0.f ? e : 0.2f * e;
        lm = fmaxf(lm, e);
    }
    for (int o = 16; o; o >>= 1) lm = fmaxf(lm, __shfl_down(lm, o, 32));
    if (ii == 0) sm[hh] = lm;
    __syncthreads();
    float mh = sm[hh];
    float lz = 0.f;
    for (int i = ii; i < deg; i += 32) {
        int s = csr_src[rs + i];
        float e = als[s * 8 + hh] + adh;
        e = e >= 0.f ? e : 0.2f * e;
        lz += expf(e - mh);
    }
    for (int o = 16; o; o >>= 1) lz += __shfl_down(lz, o, 32);
    if (ii == 0) sz[hh] = lz;
    __syncthreads();
    float inv_z = 1.0f / (sz[hh] + 1e-16f);
    float acc[8] = {0.f, 0.f, 0.f, 0.f, 0.f, 0.f, 0.f, 0.f};
    for (int i = 0; i < deg; ++i) {
        int s = csr_src[rs + i];
        float e = als[s * 8 + hh] + adh;
        e = e >= 0.f ? e : 0.2f * e;
        float w = expf(e - mh) * inv_z;
        ushortx8 hv = *(const ushortx8*)&h1b[(size_t)s * 2048 + t * 8];
#pragma unroll
        for (int j = 0; j < 8; ++j) acc[j] += w * bf2f(hv[j]);
    }
    ushortx8 o8;
#pragma unroll
    for (int j = 0; j < 8; ++j) {
        float v = acc[j] + b1[t * 8 + j];
        v = v > 0.f ? v : expm1f(v);
        o8[j] = f2bf(v);
    }
    *(ushortx8*)&out1b[(size_t)n * 2048 + t * 8] = o8;
}

__global__ void k_agg2(const int* __restrict__ row_start, const int* __restrict__ csr_src,
                       const float* __restrict__ als, const float* __restrict__ ald,
                       const unsigned short* __restrict__ x2b, const float* __restrict__ b2,
                       unsigned short* __restrict__ out2b) {
    int n = blockIdx.x, t = threadIdx.x;
    int rs = row_start[n];
    int deg = row_start[n + 1] - rs;
    float adn = ald[n];
    float lm = -1e30f;
    for (int i = t; i < deg; i += 64) {
        float e = als[csr_src[rs + i]] + adn;
        e = e >= 0.f ? e : 0.2f * e;
        lm = fmaxf(lm, e);
    }
    for (int o = 32; o; o >>= 1) lm = fmaxf(lm, __shfl_down(lm, o, 64));
    float mh = __shfl(lm, 0, 64);
    float lz = 0.f;
    for (int i = t; i < deg; i += 64) {
        float e = als[csr_src[rs + i]] + adn;
        e = e >= 0.f ? e : 0.2f * e;
        lz += expf(e - mh);
    }
    for (int o = 32; o; o >>= 1) lz += __shfl_down(lz, o, 64);
    float zz = __shfl(lz, 0, 64);
    float inv_z = 1.0f / (zz + 1e-16f);
    float acc[4] = {0.f, 0.f, 0.f, 0.f};
    for (int i = 0; i < deg; ++i) {
        int s = csr_src[rs + i];
        float e = als[s] + adn;
        e = e >= 0.f ? e : 0.2f * e;
        float w = expf(e - mh) * inv_z;
        ushortx4 hv = *(const ushortx4*)&x2b[(size_t)s * 256 + t * 4];
#pragma unroll
        for (int j = 0; j < 4; ++j) acc[j] += w * bf2f(hv[j]);
    }
    ushortx4 o4;
#pragma unroll
    for (int j = 0; j < 4; ++j) o4[j] = f2bf(acc[j] + b2[t * 4 + j]);
    *(ushortx4*)&out2b[(size_t)n * 256 + t * 4] = o4;
}

// ---------------- LSTM weight repack ----------------
// WhhR frag layout: frag id F = ((s*4 + w)*8 + k0)*4 + f  (s=col-slice, w=wave,
// k0=K-chunk, f=gate). Within a frag: 64 lanes x 8 bf16 (16B) in lane order, so a
// wave's ds_write/ds_read at lane*16 is linear and conflict-free.
// Source element: gate-col = f*256 + s*64 + w*16 + c16, k = k0*32 + q*8.
__global__ void k_repack_whh(const unsigned short* __restrict__ Whhb,
                             unsigned short* __restrict__ WhhR) {
    int i = blockIdx.x * 256 + threadIdx.x;    // 32768 threads = 512 frags x 64 lanes
    int lane = i & 63;
    int fi = i >> 6;                            // 0..511
    int f = fi & 3, k0 = (fi >> 2) & 7, w = (fi >> 5) & 3, s = fi >> 7;
    int q = lane >> 4, c16 = lane & 15;
    int gcol = f * 256 + s * 64 + w * 16 + c16;
    int k = k0 * 32 + q * 8;
    ushortx8 v = *(const ushortx8*)&Whhb[(size_t)gcol * 256 + k];
    *(ushortx8*)&WhhR[(size_t)fi * 512 + lane * 8] = v;
}

// ---------------- LSTM recurrence, v9: tag-in-data exchange (1 L3 round trip/step) ----
// Topology of v8 (64 blocks = 16 batch-groups x 4 col-slices; 128KB LDS-resident
// Whh slice; sc0/sc1 write-through exchange -- v8 measured 208us, 7.8k cy/step).
// v8's residual cost: 4-5 SERIALIZED L3 round trips per step (store flight ->
// producer vmcnt drain -> flag RMW -> consumer poll detect -> h load). The data
// itself arrives in the first one.
// v9 collapses publish+detect+load into the load itself: h is stored as a packed
// dword (tag<<16)|bf16 where tag = t+1. Consumers speculatively load the packed
// words they need (sc1, straight from L3) and retry until EVERY word carries the
// right tag -- per-element tags make store completion order irrelevant, so the
// producer needs NO drain, NO barrier, NO flag. Ring slots are written once and
// pre-zeroed (tag 0 never valid), so stale reads self-identify. Retries are
// throttled with s_sleep(2) and bounded (stall -> wrong data + counters, not a
// hang; all 64 blocks are co-resident anyway at 1 block/CU).
// t=63 skips the packed store and writes plain bf16 hTb for the projection GEMM.

__global__ __launch_bounds__(256, 1) void k_lstm9(
    const float* __restrict__ Xg, const unsigned short* __restrict__ WhhR,
    unsigned* __restrict__ hP, unsigned short* __restrict__ hTb) {
    __shared__ unsigned short wlds[4 * 32 * 512];   // 128KB: [wave][k0*4+f][lane*8]

    int tid = threadIdx.x;
    int w = tid >> 6, lane = tid & 63;
    int q = lane >> 4, c16 = lane & 15;
    int g = blockIdx.x & 15, s = blockIdx.x >> 4;
    int scol = s * 64 + w * 16 + c16;               // h-col this lane owns

    // one-time preload of this wave's 32 weight frags (32KB) into LDS
    const unsigned short* wsrc = WhhR + (size_t)((s * 4 + w) * 32) * 512 + lane * 8;
#pragma unroll
    for (int fi = 0; fi < 32; ++fi)
        *(shortx8*)&wlds[(w * 32 + fi) * 512 + lane * 8] =
            *(const shortx8*)(wsrc + fi * 512);
    __syncthreads();

    float cst[4] = {0.f, 0.f, 0.f, 0.f};

    for (int t = 0; t < SL; ++t) {
        // Xg prefetch (normal cached loads; latency hides under the poll/MFMA)
        float xg[4][4];
#pragma unroll
        for (int r = 0; r < 4; ++r) {
            const float* xp = Xg + ((size_t)(g * 16 + q * 4 + r) * SL + t) * 1024 + scol;
#pragma unroll
            for (int f = 0; f < 4; ++f) xg[r][f] = xp[f * 256];
        }

        floatx4 acc[4] = {};
        if (t > 0) {
            // speculative tagged load of h[t-1]: row g*16+c16, all 256 cols.
            // 8 chunks x 8 packed dwords = 16x dwordx4. Retry until all tags == t.
            const unsigned* hp = hP + ((size_t)(t - 1) * 256 + g * 16 + c16) * 256;
            unsigned tag = (unsigned)t;             // slot t-1 carries tag (t-1)+1
            uintx4 pk[16];
            int tries = 0;
            for (;;) {
#pragma unroll
                for (int k0 = 0; k0 < 8; ++k0)
#pragma unroll
                    for (int h2 = 0; h2 < 2; ++h2)
                        pk[k0 * 2 + h2] = load_b128_sys_u(hp + k0 * 32 + q * 8 + h2 * 4);
                asm volatile("s_waitcnt vmcnt(0)" ::: "memory");
                bool good = true;
#pragma unroll
                for (int j = 0; j < 16; ++j)
#pragma unroll
                    for (int e = 0; e < 4; ++e) good &= ((pk[j][e] >> 16) == tag);
                if (__all((int)good) || ++tries > 50000) break;
                __builtin_amdgcn_s_sleep(2);
            }
            __builtin_amdgcn_sched_barrier(0);

            // unpack low16 -> bf16 A-frags, MFMA against LDS-resident weights
#pragma unroll
            for (int k0 = 0; k0 < 8; ++k0) {
                shortx8 a;
#pragma unroll
                for (int e = 0; e < 8; ++e)
                    a[e] = (short)(pk[k0 * 2 + (e >> 2)][e & 3] & 0xffffu);
#pragma unroll
                for (int f = 0; f < 4; ++f) {
                    shortx8 b = *(const shortx8*)&wlds[(w * 32 + k0 * 4 + f) * 512 + lane * 8];
                    acc[f] = __builtin_amdgcn_mfma_f32_16x16x32_bf16(a, b, acc[f], 0, 0, 0);
                }
            }
        }

        // epilogue: gates -> c,h for rows q*4+r, col scol
        unsigned* hw = hP + ((size_t)t * 256 + g * 16) * 256 + scol;
#pragma unroll
        for (int r = 0; r < 4; ++r) {
            float gi = acc[0][r] + xg[r][0];
            float gf = acc[1][r] + xg[r][1];
            float gG = acc[2][r] + xg[r][2];
            float go = acc[3][r] + xg[r][3];
            float si = __builtin_amdgcn_rcpf(1.f + __expf(-gi));
            float sf = __builtin_amdgcn_rcpf(1.f + __expf(-gf));
            float so = __builtin_amdgcn_rcpf(1.f + __expf(-go));
            float tg = 1.f - 2.f * __builtin_amdgcn_rcpf(1.f + __expf(2.f * gG));
            float c = sf * cst[r] + si * tg;
            cst[r] = c;
            float tc = 1.f - 2.f * __builtin_amdgcn_rcpf(1.f + __expf(2.f * c));
            unsigned short hv = f2bf(so * tc);
            if (t < SL - 1)
                store_b32_sys(hw + (q * 4 + r) * 256,
                              (((unsigned)(t + 1)) << 16) | (unsigned)hv);
            else
                hTb[(size_t)(g * 16 + q * 4 + r) * 256 + scol] = hv;   // plain store;
                // kernel boundary makes it visible to the projection GEMM
        }
        // no drain, no barrier, no flag: the tagged stores ARE the publish
    }
}

// ---------------- launch ----------------

extern "C" void kernel_launch(void* const* d_in, const int* in_sizes, int n_in,
                              void* d_out, int out_size, void* d_ws, size_t ws_size,
                              hipStream_t stream) {
    const int*   x_ids = (const int*)d_in[0];
    const int*   ei    = (const int*)d_in[1];
    const float* emb   = (const float*)d_in[3];
    const float* W1    = (const float*)d_in[4];
    const float* as1w  = (const float*)d_in[5];
    const float* ad1w  = (const float*)d_in[6];
    const float* b1    = (const float*)d_in[7];
    const float* W2    = (const float*)d_in[8];
    const float* as2w  = (const float*)d_in[9];
    const float* ad2w  = (const float*)d_in[10];
    const float* b2    = (const float*)d_in[11];
    const float* Wih   = (const float*)d_in[12];
    const float* Whh   = (const float*)d_in[13];
    const float* bih   = (const float*)d_in[14];
    const float* bhh   = (const float*)d_in[15];
    const float* Wp    = (const float*)d_in[16];
    const float* bp    = (const float*)d_in[17];

    char* ws = (char*)d_ws;
    size_t off = 0;
    auto alloc = [&](size_t bytes) -> void* {
        void* p = ws + off;
        off += (bytes + 255) & ~(size_t)255;
        return p;
    };
    unsigned short* h1b   = (unsigned short*)alloc((size_t)NN * 2048 * 2);  // reused as Xg
    float*          Xg    = (float*)h1b;
    unsigned short* out1b = (unsigned short*)alloc((size_t)NN * 2048 * 2);
    unsigned short* xb    = (unsigned short*)alloc((size_t)NN * 256 * 2);
    unsigned short* x2b   = (unsigned short*)alloc((size_t)NN * 256 * 2);
    unsigned short* out2b = (unsigned short*)alloc((size_t)NN * 256 * 2);
    unsigned short* W1t   = (unsigned short*)alloc((size_t)2048 * 256 * 2);
    unsigned short* W2t   = (unsigned short*)alloc((size_t)256 * 2048 * 2);
    unsigned short* Wihb  = (unsigned short*)alloc((size_t)1024 * 256 * 2);
    unsigned short* Whhb  = (unsigned short*)alloc((size_t)1024 * 256 * 2);
    unsigned short* WhhR  = (unsigned short*)alloc((size_t)1024 * 256 * 2);
    unsigned short* Wpb   = (unsigned short*)alloc((size_t)37000 * 256 * 2);
    float*          bb    = (float*)alloc(1024 * 4);
    float*          als1  = (float*)alloc((size_t)NN * 8 * 4);
    float*          ald1  = (float*)alloc((size_t)NN * 8 * 4);
    float*          als2  = (float*)alloc((size_t)NN * 4);
    float*          ald2  = (float*)alloc((size_t)NN * 4);
    unsigned*       hP    = (unsigned*)alloc((size_t)SL * 256 * 256 * 4);   // tagged h ring, 16MB
    unsigned short* hTb   = (unsigned short*)alloc((size_t)256 * 256 * 2);
    int* deg       = (int*)alloc((size_t)NN * 4);
    int* row_start = (int*)alloc((size_t)(NN + 1) * 4);
    int* cursor    = (int*)alloc((size_t)NN * 4);
    int* csr_src   = (int*)alloc((size_t)NTOT * 4);
    (void)ws_size; (void)in_sizes; (void)n_in; (void)out_size;

    // weight prep
    k_transpose_bf16<<<dim3(2048 / 32, 256 / 32), dim3(32, 8), 0, stream>>>(W1, W1t, 256, 2048);
    k_transpose_bf16<<<dim3(256 / 32, 2048 / 32), dim3(32, 8), 0, stream>>>(W2, W2t, 2048, 256);
    k_cast_bf16<<<(262144 / 4 + 255) / 256, 256, 0, stream>>>(Wih, Wihb, 262144 / 4);
    k_cast_bf16<<<(262144 / 4 + 255) / 256, 256, 0, stream>>>(Whh, Whhb, 262144 / 4);
    k_cast_bf16<<<(9472000 / 4 + 255) / 256, 256, 0, stream>>>(Wp, Wpb, 9472000 / 4);
    k_add2<<<4, 256, 0, stream>>>(bih, bhh, bb, 1024);
    k_repack_whh<<<32768 / 256, 256, 0, stream>>>(Whhb, WhhR);
    k_zero<<<(SL * 256 * 256) / 256, 256, 0, stream>>>((int*)hP, SL * 256 * 256);
    // ^ tag 0 != any valid tag (valid tags are 1..63); re-zeroed every launch

    // CSR
    k_deg_init<<<NN / 256, 256, 0, stream>>>(deg);
    k_deg_count<<<NE / 256, 256, 0, stream>>>(ei, deg);
    k_scan<<<1, 1024, 0, stream>>>(deg, row_start, cursor);
    k_fill<<<(NTOT + 255) / 256, 256, 0, stream>>>(ei, cursor, csr_src);

    // embedding gather
    k_gather_x<<<NN * 64 / 256, 256, 0, stream>>>(x_ids, emb, xb);

    // GAT layer 1
    k_gemm_bt<true, false><<<dim3(NN / 128, 2048 / 128), 256, 0, stream>>>(
        xb, W1t, h1b, nullptr, NN, 2048, 256);
    k_alpha1<<<NN, 256, 0, stream>>>(h1b, as1w, ad1w, als1, ald1);
    k_agg1<<<NN, 256, 0, stream>>>(row_start, csr_src, als1, ald1, h1b, b1, out1b);

    // GAT layer 2
    k_gemm_bt<true, false><<<dim3(NN / 128, 256 / 128), 256, 0, stream>>>(
        out1b, W2t, x2b, nullptr, NN, 256, 2048);
    k_alpha2<<<NN, 64, 0, stream>>>(x2b, as2w, ad2w, als2, ald2);
    k_agg2<<<NN, 64, 0, stream>>>(row_start, csr_src, als2, ald2, x2b, b2, out2b);

    // LSTM: Xg = out2 @ Wih^T + (bih + bhh)
    k_gemm_bt<false, true><<<dim3(NN / 128, 1024 / 128), 256, 0, stream>>>(
        out2b, Wihb, Xg, bb, NN, 1024, 256);
    k_lstm9<<<64, 256, 0, stream>>>(Xg, WhhR, hP, hTb);

    // final projection
    k_gemm_bt<false, true><<<dim3(256 / 128, (37000 + 127) / 128), 256, 0, stream>>>(
        hTb, Wpb, (float*)d_out, bp, 256, 37000, 256);
}

// Round 8
// 618.354 us; speedup vs baseline: 1.2778x; 1.2778x over previous
//
#include <hip/hip_runtime.h>
#include <hip/hip_bf16.h>
#include <cstdint>

#define HD 256
#define NHEADS 8
#define NB 256
#define SL 64
#define NN 16384
#define NE 131072
#define NTOT (NE + NN)   // 147456

typedef float floatx4 __attribute__((ext_vector_type(4)));
typedef short shortx8 __attribute__((ext_vector_type(8)));
typedef unsigned short ushortx8 __attribute__((ext_vector_type(8)));
typedef unsigned short ushortx4 __attribute__((ext_vector_type(4)));

__device__ __forceinline__ unsigned short f2bf(float f) {
    union { float f; unsigned u; } a; a.f = f;
    unsigned r = a.u + 0x7fffu + ((a.u >> 16) & 1u);
    return (unsigned short)(r >> 16);
}
__device__ __forceinline__ float bf2f(unsigned short b) {
    union { unsigned u; float f; } a; a.u = ((unsigned)b) << 16;
    return a.f;
}

// system-coherent (write-through / L2-bypass) accessors for cross-block h exchange.
// sc0 sc1 => the access happens at the coherence point (L3/IC); L2 is never dirty
// and never serves stale lines, so no buffer_wbl2/buffer_inv walks are needed.
// (v7 measured those walks at 13.6k cy/step; v8 with this protocol = 7.8k cy/step.)
__device__ __forceinline__ void store_b16_sys(unsigned short* p, unsigned v) {
    asm volatile("global_store_short %0, %1, off sc0 sc1" :: "v"(p), "v"(v) : "memory");
}
__device__ __forceinline__ shortx8 load_b128_sys(const unsigned short* p) {
    shortx8 r;
    asm volatile("global_load_dwordx4 %0, %1, off sc0 sc1" : "=v"(r) : "v"(p) : "memory");
    return r;
}

// ---------------- conversions ----------------

__global__ void k_cast_bf16(const float* __restrict__ in, unsigned short* __restrict__ out, int n4) {
    int i = blockIdx.x * 256 + threadIdx.x;
    if (i >= n4) return;
    float4 v = ((const float4*)in)[i];
    ushortx4 o;
    o[0] = f2bf(v.x); o[1] = f2bf(v.y); o[2] = f2bf(v.z); o[3] = f2bf(v.w);
    *(ushortx4*)&out[i * 4] = o;
}

// out[n][k] = bf16(in[k][n]); in is K x N fp32. grid (N/32, K/32), block (32,8)
__global__ void k_transpose_bf16(const float* __restrict__ in, unsigned short* __restrict__ out,
                                 int K, int N) {
    __shared__ float t[32][33];
    int nb = blockIdx.x * 32, kb = blockIdx.y * 32;
    int tx = threadIdx.x, ty = threadIdx.y;
#pragma unroll
    for (int i = 0; i < 4; ++i) {
        int k = kb + ty + i * 8;
        t[ty + i * 8][tx] = in[(size_t)k * N + nb + tx];
    }
    __syncthreads();
#pragma unroll
    for (int i = 0; i < 4; ++i) {
        int nrow = nb + ty + i * 8;
        out[(size_t)nrow * K + kb + tx] = f2bf(t[tx][ty + i * 8]);
    }
}

__global__ void k_add2(const float* __restrict__ a, const float* __restrict__ b,
                       float* __restrict__ o, int n) {
    int i = blockIdx.x * 256 + threadIdx.x;
    if (i < n) o[i] = a[i] + b[i];
}

__global__ void k_zero(int* __restrict__ p, int n) {
    int i = blockIdx.x * 256 + threadIdx.x;
    if (i < n) p[i] = 0;
}

// x_b[n][d] = bf16(emb[x_ids[n]][d]), row 0 of emb forced to 0
__global__ void k_gather_x(const int* __restrict__ ids, const float* __restrict__ emb,
                           unsigned short* __restrict__ xb) {
    int i = blockIdx.x * 256 + threadIdx.x;   // over NN*64
    int n = i >> 6, d4 = (i & 63) << 2;
    int id = ids[n];
    float4 v = make_float4(0.f, 0.f, 0.f, 0.f);
    if (id != 0) v = *(const float4*)&emb[(size_t)id * HD + d4];
    ushortx4 o;
    o[0] = f2bf(v.x); o[1] = f2bf(v.y); o[2] = f2bf(v.z); o[3] = f2bf(v.w);
    *(ushortx4*)&xb[(size_t)n * HD + d4] = o;
}

// ---------------- GEMM: C(MxN) = A(MxK bf16) * B^T  (B given as N x K bf16) ----------------

template <bool OUT_BF16, bool HAS_BIAS>
__global__ __launch_bounds__(256, 2) void k_gemm_bt(
    const unsigned short* __restrict__ A, const unsigned short* __restrict__ B,
    void* __restrict__ C, const float* __restrict__ bias, int M, int Nn, int K) {
    constexpr int LDT = 56;
    __shared__ unsigned short As[128 * LDT];
    __shared__ unsigned short Bs[128 * LDT];
    int tid = threadIdx.x;
    int wave = tid >> 6, lane = tid & 63;
    int q = lane >> 4, c16 = lane & 15;
    long m0 = (long)blockIdx.x * 128;
    long n0 = (long)blockIdx.y * 128;
    int wm = (wave & 1) << 6, wn = (wave >> 1) << 6;
    floatx4 acc[4][4] = {};
    int lrow = tid >> 2;
    int lk = (tid & 3) << 3;
    const unsigned short* Arow0 = A + (m0 + lrow) * K + lk;
    const unsigned short* Arow1 = A + (m0 + 64 + lrow) * K + lk;
    long nb0 = n0 + lrow;      if (nb0 >= Nn) nb0 = Nn - 1;
    long nb1 = n0 + 64 + lrow; if (nb1 >= Nn) nb1 = Nn - 1;
    const unsigned short* Brow0 = B + nb0 * K + lk;
    const unsigned short* Brow1 = B + nb1 * K + lk;

    for (int k0 = 0; k0 < K; k0 += 32) {
        ushortx8 a0 = *(const ushortx8*)(Arow0 + k0);
        ushortx8 a1 = *(const ushortx8*)(Arow1 + k0);
        ushortx8 b0 = *(const ushortx8*)(Brow0 + k0);
        ushortx8 b1 = *(const ushortx8*)(Brow1 + k0);
        __syncthreads();
        *(ushortx8*)&As[lrow * LDT + lk] = a0;
        *(ushortx8*)&As[(64 + lrow) * LDT + lk] = a1;
        *(ushortx8*)&Bs[lrow * LDT + lk] = b0;
        *(ushortx8*)&Bs[(64 + lrow) * LDT + lk] = b1;
        __syncthreads();
        shortx8 af[4], bfr[4];
#pragma unroll
        for (int mt = 0; mt < 4; ++mt)
            af[mt] = *(const shortx8*)&As[(wm + mt * 16 + c16) * LDT + q * 8];
#pragma unroll
        for (int nt = 0; nt < 4; ++nt)
            bfr[nt] = *(const shortx8*)&Bs[(wn + nt * 16 + c16) * LDT + q * 8];
#pragma unroll
        for (int mt = 0; mt < 4; ++mt)
#pragma unroll
            for (int nt = 0; nt < 4; ++nt)
                acc[mt][nt] = __builtin_amdgcn_mfma_f32_16x16x32_bf16(af[mt], bfr[nt], acc[mt][nt], 0, 0, 0);
    }
#pragma unroll
    for (int mt = 0; mt < 4; ++mt) {
        long row_base = m0 + wm + mt * 16 + q * 4;
#pragma unroll
        for (int nt = 0; nt < 4; ++nt) {
            long col = n0 + wn + nt * 16 + c16;
            if (col >= Nn) continue;
            float bv = HAS_BIAS ? bias[col] : 0.0f;
#pragma unroll
            for (int r = 0; r < 4; ++r) {
                float v = acc[mt][nt][r] + bv;
                long idx = (row_base + r) * (long)Nn + col;
                if (OUT_BF16) ((unsigned short*)C)[idx] = f2bf(v);
                else          ((float*)C)[idx] = v;
            }
        }
    }
}

// ---------------- batched per-head GEMM: out1[n][hh*256+j] = ELU(aggx[hh] @ W1_hh + b1) ----
// A = aggxb + hh*NN*256 (NN x 256 bf16), B = W1t + hh*256*256 (256 x 256 bf16, row = out col),
// C = out1b (NN x 2048 bf16), grid (NN/128, 2, 8).
__global__ __launch_bounds__(256, 2) void k_gemm_b8(
    const unsigned short* __restrict__ Ab, const unsigned short* __restrict__ W1t,
    unsigned short* __restrict__ C, const float* __restrict__ b1) {
    constexpr int LDT = 56;
    __shared__ unsigned short As[128 * LDT];
    __shared__ unsigned short Bs[128 * LDT];
    int tid = threadIdx.x;
    int wave = tid >> 6, lane = tid & 63;
    int q = lane >> 4, c16 = lane & 15;
    int hh = blockIdx.z;
    const unsigned short* A = Ab + (size_t)hh * NN * 256;
    const unsigned short* B = W1t + (size_t)hh * 256 * 256;
    long m0 = (long)blockIdx.x * 128;
    long n0 = (long)blockIdx.y * 128;   // within head (Nn = 256)
    int wm = (wave & 1) << 6, wn = (wave >> 1) << 6;
    floatx4 acc[4][4] = {};
    int lrow = tid >> 2;
    int lk = (tid & 3) << 3;
    const unsigned short* Arow0 = A + (m0 + lrow) * 256 + lk;
    const unsigned short* Arow1 = A + (m0 + 64 + lrow) * 256 + lk;
    const unsigned short* Brow0 = B + (n0 + lrow) * 256 + lk;
    const unsigned short* Brow1 = B + (n0 + 64 + lrow) * 256 + lk;

    for (int k0 = 0; k0 < 256; k0 += 32) {
        ushortx8 a0 = *(const ushortx8*)(Arow0 + k0);
        ushortx8 a1 = *(const ushortx8*)(Arow1 + k0);
        ushortx8 b0 = *(const ushortx8*)(Brow0 + k0);
        ushortx8 b1 = *(const ushortx8*)(Brow1 + k0);
        __syncthreads();
        *(ushortx8*)&As[lrow * LDT + lk] = a0;
        *(ushortx8*)&As[(64 + lrow) * LDT + lk] = a1;
        *(ushortx8*)&Bs[lrow * LDT + lk] = b0;
        *(ushortx8*)&Bs[(64 + lrow) * LDT + lk] = b1;
        __syncthreads();
        shortx8 af[4], bfr[4];
#pragma unroll
        for (int mt = 0; mt < 4; ++mt)
            af[mt] = *(const shortx8*)&As[(wm + mt * 16 + c16) * LDT + q * 8];
#pragma unroll
        for (int nt = 0; nt < 4; ++nt)
            bfr[nt] = *(const shortx8*)&Bs[(wn + nt * 16 + c16) * LDT + q * 8];
#pragma unroll
        for (int mt = 0; mt < 4; ++mt)
#pragma unroll
            for (int nt = 0; nt < 4; ++nt)
                acc[mt][nt] = __builtin_amdgcn_mfma_f32_16x16x32_bf16(af[mt], bfr[nt], acc[mt][nt], 0, 0, 0);
    }
#pragma unroll
    for (int mt = 0; mt < 4; ++mt) {
        long row_base = m0 + wm + mt * 16 + q * 4;
#pragma unroll
        for (int nt = 0; nt < 4; ++nt) {
            int gcol = hh * 256 + (int)(n0 + wn + nt * 16 + c16);
            float bv = b1[gcol];
#pragma unroll
            for (int r = 0; r < 4; ++r) {
                float v = acc[mt][nt][r] + bv;
                v = v > 0.f ? v : expm1f(v);   // ELU fused (layer-1 activation)
                C[(row_base + r) * 2048 + gcol] = f2bf(v);
            }
        }
    }
}

// ---------------- layer-1 attention-vector build ----------------
// Vb[o][k] = sum_d W1[k][hh*256+d] * a[hh][d]   (o<8: a=att_src1, hh=o; o>=8: att_dst1, hh=o-8)
// Then als1[n][hh] = x[n] . Vb[hh], ald1[n][hh] = x[n] . Vb[8+hh]  (computed via dots GEMM) --
// mathematically identical to (x W1) . a, so h1 never needs to be materialized.
__global__ void k_build_v(const float* __restrict__ W1, const float* __restrict__ as1,
                          const float* __restrict__ ad1, unsigned short* __restrict__ Vb) {
    __shared__ float av[256];
    int o = blockIdx.x, k = threadIdx.x;
    int hh = o & 7;
    const float* a = (o < 8) ? as1 : ad1;
    av[k] = a[hh * 256 + k];
    __syncthreads();
    const float* wrow = W1 + (size_t)k * 2048 + hh * 256;
    float sum = 0.f;
#pragma unroll 8
    for (int d = 0; d < 256; ++d) sum += wrow[d] * av[d];
    Vb[o * 256 + k] = f2bf(sum);
}

// ---------------- attention dots (layer 2) ----------------

__global__ void k_alpha2(const unsigned short* __restrict__ x2b, const float* __restrict__ asrc,
                         const float* __restrict__ adst, float* __restrict__ als,
                         float* __restrict__ ald) {
    int n = blockIdx.x, t = threadIdx.x;
    ushortx4 hv = *(const ushortx4*)&x2b[(size_t)n * 256 + t * 4];
    float s = 0.f, d = 0.f;
#pragma unroll
    for (int j = 0; j < 4; ++j) {
        float f = bf2f(hv[j]);
        s += f * asrc[t * 4 + j];
        d += f * adst[t * 4 + j];
    }
    for (int o = 32; o; o >>= 1) { s += __shfl_down(s, o, 64); d += __shfl_down(d, o, 64); }
    if (t == 0) { als[n] = s; ald[n] = d; }
}

// ---------------- CSR build ----------------

__global__ void k_deg_init(int* __restrict__ deg) {
    int i = blockIdx.x * 256 + threadIdx.x;
    if (i < NN) deg[i] = 1;
}
__global__ void k_deg_count(const int* __restrict__ ei, int* __restrict__ deg) {
    int e = blockIdx.x * 256 + threadIdx.x;
    if (e < NE) atomicAdd(&deg[ei[NE + e]], 1);
}
__global__ void k_scan(const int* __restrict__ deg, int* __restrict__ row_start,
                       int* __restrict__ cursor) {
    __shared__ int s[1024];
    int t = threadIdx.x;
    int base = t * 16;
    int loc[16]; int sum = 0;
#pragma unroll
    for (int i = 0; i < 16; ++i) { loc[i] = deg[base + i]; sum += loc[i]; }
    s[t] = sum;
    __syncthreads();
    for (int o = 1; o < 1024; o <<= 1) {
        int v = (t >= o) ? s[t - o] : 0;
        __syncthreads();
        s[t] += v;
        __syncthreads();
    }
    int ex = s[t] - sum;
#pragma unroll
    for (int i = 0; i < 16; ++i) {
        row_start[base + i] = ex;
        cursor[base + i] = ex;
        ex += loc[i];
    }
    if (t == 0) row_start[NN] = NTOT;
}
__global__ void k_fill(const int* __restrict__ ei, int* __restrict__ cursor,
                       int* __restrict__ csr_src) {
    int e = blockIdx.x * 256 + threadIdx.x;
    if (e >= NTOT) return;
    int s, d;
    if (e < NE) { s = ei[e]; d = ei[NE + e]; }
    else        { s = e - NE; d = s; }
    int p = atomicAdd(&cursor[d], 1);
    csr_src[p] = s;
}

// ---------------- GAT layer-1 aggregation over x (256-wide, pre-projection) ----------------
// out per head: aggx[hh][n][:] = sum_src alpha[hh,src->n] * x[src][:].
// Identical math to aggregating h1 = xW1 then never needed: (sum a x) W1 == sum a (x W1).
// Traffic: NTOT x 512B = 75MB instead of NTOT x 4KB = 604MB (the old k_agg1).
// D[n][0..7] = als1 (x.V_src), D[n][8..15] = ald1 (x.V_dst), from the dots GEMM.
__global__ __launch_bounds__(256) void k_aggx(
    const int* __restrict__ row_start, const int* __restrict__ csr_src,
    const float* __restrict__ D, const unsigned short* __restrict__ xb,
    unsigned short* __restrict__ aggxb) {
    int n = blockIdx.x, t = threadIdx.x;
    int rs = row_start[n];
    int deg = row_start[n + 1] - rs;
    __shared__ float sad[8], sm[8], sinvz[8];
    __shared__ int sed[32];
    __shared__ float wlds[32][8];
    if (t < 8) sad[t] = D[n * 16 + 8 + t];
    __syncthreads();
    int hh = t >> 5, ii = t & 31;
    float adh = sad[hh];
    float lm = -1e30f;
    for (int i = ii; i < deg; i += 32) {
        int s = csr_src[rs + i];
        float e = D[s * 16 + hh] + adh;
        e = e >= 0.f ? e : 0.2f * e;
        lm = fmaxf(lm, e);
    }
    for (int o = 16; o; o >>= 1) lm = fmaxf(lm, __shfl_down(lm, o, 32));
    if (ii == 0) sm[hh] = lm;
    __syncthreads();
    float mh = sm[hh];
    float lz = 0.f;
    for (int i = ii; i < deg; i += 32) {
        int s = csr_src[rs + i];
        float e = D[s * 16 + hh] + adh;
        e = e >= 0.f ? e : 0.2f * e;
        lz += expf(e - mh);
    }
    for (int o = 16; o; o >>= 1) lz += __shfl_down(lz, o, 32);
    if (ii == 0) sinvz[hh] = 1.0f / (lz + 1e-16f);
    __syncthreads();

    float acc[8] = {0.f, 0.f, 0.f, 0.f, 0.f, 0.f, 0.f, 0.f};
    int eh = t & 7, ee = t >> 3;           // weight phase: 32 edges x 8 heads
    for (int base = 0; base < deg; base += 32) {
        int cnt = min(32, deg - base);
        if (t < 32) sed[t] = (t < cnt) ? csr_src[rs + base + t] : 0;
        __syncthreads();
        if (ee < cnt) {
            int s = sed[ee];
            float e = D[s * 16 + eh] + sad[eh];
            e = e >= 0.f ? e : 0.2f * e;
            wlds[ee][eh] = expf(e - sm[eh]) * sinvz[eh];
        }
        __syncthreads();
        for (int e = 0; e < cnt; ++e) {
            float xv = bf2f(xb[(size_t)sed[e] * 256 + t]);
#pragma unroll
            for (int h = 0; h < 8; ++h) acc[h] += wlds[e][h] * xv;
        }
        __syncthreads();
    }
#pragma unroll
    for (int h = 0; h < 8; ++h)
        aggxb[((size_t)h * NN + n) * 256 + t] = f2bf(acc[h]);
}

// ---------------- GAT layer-2 aggregation (unchanged; already post-projection) ----------------

__global__ void k_agg2(const int* __restrict__ row_start, const int* __restrict__ csr_src,
                       const float* __restrict__ als, const float* __restrict__ ald,
                       const unsigned short* __restrict__ x2b, const float* __restrict__ b2,
                       unsigned short* __restrict__ out2b) {
    int n = blockIdx.x, t = threadIdx.x;
    int rs = row_start[n];
    int deg = row_start[n + 1] - rs;
    float adn = ald[n];
    float lm = -1e30f;
    for (int i = t; i < deg; i += 64) {
        float e = als[csr_src[rs + i]] + adn;
        e = e >= 0.f ? e : 0.2f * e;
        lm = fmaxf(lm, e);
    }
    for (int o = 32; o; o >>= 1) lm = fmaxf(lm, __shfl_down(lm, o, 64));
    float mh = __shfl(lm, 0, 64);
    float lz = 0.f;
    for (int i = t; i < deg; i += 64) {
        float e = als[csr_src[rs + i]] + adn;
        e = e >= 0.f ? e : 0.2f * e;
        lz += expf(e - mh);
    }
    for (int o = 32; o; o >>= 1) lz += __shfl_down(lz, o, 64);
    float zz = __shfl(lz, 0, 64);
    float inv_z = 1.0f / (zz + 1e-16f);
    float acc[4] = {0.f, 0.f, 0.f, 0.f};
    for (int i = 0; i < deg; ++i) {
        int s = csr_src[rs + i];
        float e = als[s] + adn;
        e = e >= 0.f ? e : 0.2f * e;
        float w = expf(e - mh) * inv_z;
        ushortx4 hv = *(const ushortx4*)&x2b[(size_t)s * 256 + t * 4];
#pragma unroll
        for (int j = 0; j < 4; ++j) acc[j] += w * bf2f(hv[j]);
    }
    ushortx4 o4;
#pragma unroll
    for (int j = 0; j < 4; ++j) o4[j] = f2bf(acc[j] + b2[t * 4 + j]);
    *(ushortx4*)&out2b[(size_t)n * 256 + t * 4] = o4;
}

// ---------------- LSTM weight repack ----------------
__global__ void k_repack_whh(const unsigned short* __restrict__ Whhb,
                             unsigned short* __restrict__ WhhR) {
    int i = blockIdx.x * 256 + threadIdx.x;    // 32768 threads = 512 frags x 64 lanes
    int lane = i & 63;
    int fi = i >> 6;                            // 0..511
    int f = fi & 3, k0 = (fi >> 2) & 7, w = (fi >> 5) & 3, s = fi >> 7;
    int q = lane >> 4, c16 = lane & 15;
    int gcol = f * 256 + s * 64 + w * 16 + c16;
    int k = k0 * 32 + q * 8;
    ushortx8 v = *(const ushortx8*)&Whhb[(size_t)gcol * 256 + k];
    *(ushortx8*)&WhhR[(size_t)fi * 512 + lane * 8] = v;
}

// ---------------- LSTM recurrence, v8 (VERBATIM -- proven 208us, absmax-identical) -------
// 64 blocks = 16 batch-groups x 4 col-slices; 128KB LDS-resident Whh slice;
// sc0/sc1 write-through exchange; flag counters; no cache-maintenance walks.
// (v9's tag-in-data retry loop regressed to 343us: each failed probe was itself a
// full 16-load L3 round trip + 16KB refetch. Reverted.)

__global__ __launch_bounds__(256, 1) void k_lstm8(
    const float* __restrict__ Xg, const unsigned short* __restrict__ WhhR,
    unsigned short* __restrict__ hX, int* __restrict__ flags) {
    __shared__ unsigned short wlds[4 * 32 * 512];   // 128KB: [wave][k0*4+f][lane*8]

    int tid = threadIdx.x;
    int w = tid >> 6, lane = tid & 63;
    int q = lane >> 4, c16 = lane & 15;
    int g = blockIdx.x & 15, s = blockIdx.x >> 4;
    int scol = s * 64 + w * 16 + c16;               // h-col this lane owns
    const int fbase = g * 64;

    const unsigned short* wsrc = WhhR + (size_t)((s * 4 + w) * 32) * 512 + lane * 8;
#pragma unroll
    for (int fi = 0; fi < 32; ++fi)
        *(shortx8*)&wlds[(w * 32 + fi) * 512 + lane * 8] =
            *(const shortx8*)(wsrc + fi * 512);

    float cst[4] = {0.f, 0.f, 0.f, 0.f};

    for (int t = 0; t < SL; ++t) {
        float xg[4][4];
#pragma unroll
        for (int r = 0; r < 4; ++r) {
            const float* xp = Xg + ((size_t)(g * 16 + q * 4 + r) * SL + t) * 1024 + scol;
#pragma unroll
            for (int f = 0; f < 4; ++f) xg[r][f] = xp[f * 256];
        }

        floatx4 acc[4] = {};
        if (t > 0) {
            if (tid == 0) {
                int spins = 0;
                while (__hip_atomic_fetch_add(&flags[fbase + t - 1], 0, __ATOMIC_RELAXED,
                                              __HIP_MEMORY_SCOPE_AGENT) < 4) {
                    __builtin_amdgcn_s_sleep(2);
                    if (++spins > 65536) break;
                }
            }
            __syncthreads();

            const unsigned short* hp =
                hX + ((size_t)(t - 1) * 256 + g * 16 + c16) * 256 + q * 8;
            shortx8 af[8];
#pragma unroll
            for (int k0 = 0; k0 < 8; ++k0) af[k0] = load_b128_sys(hp + k0 * 32);
            asm volatile("s_waitcnt vmcnt(0)" ::: "memory");
            __builtin_amdgcn_sched_barrier(0);
#pragma unroll
            for (int k0 = 0; k0 < 8; ++k0)
#pragma unroll
                for (int f = 0; f < 4; ++f) {
                    shortx8 b = *(const shortx8*)&wlds[(w * 32 + k0 * 4 + f) * 512 + lane * 8];
                    acc[f] = __builtin_amdgcn_mfma_f32_16x16x32_bf16(af[k0], b, acc[f], 0, 0, 0);
                }
        }

        unsigned short* hw = hX + ((size_t)t * 256 + g * 16) * 256 + scol;
#pragma unroll
        for (int r = 0; r < 4; ++r) {
            float gi = acc[0][r] + xg[r][0];
            float gf = acc[1][r] + xg[r][1];
            float gG = acc[2][r] + xg[r][2];
            float go = acc[3][r] + xg[r][3];
            float si = __builtin_amdgcn_rcpf(1.f + __expf(-gi));
            float sf = __builtin_amdgcn_rcpf(1.f + __expf(-gf));
            float so = __builtin_amdgcn_rcpf(1.f + __expf(-go));
            float tg = 1.f - 2.f * __builtin_amdgcn_rcpf(1.f + __expf(2.f * gG));
            float c = sf * cst[r] + si * tg;
            cst[r] = c;
            float tc = 1.f - 2.f * __builtin_amdgcn_rcpf(1.f + __expf(2.f * c));
            store_b16_sys(hw + (q * 4 + r) * 256, (unsigned)f2bf(so * tc));
        }

        if (t < SL - 1) {
            asm volatile("s_waitcnt vmcnt(0)" ::: "memory");
            __syncthreads();
            if (tid == 0)
                __hip_atomic_fetch_add(&flags[fbase + t], 1, __ATOMIC_RELAXED,
                                       __HIP_MEMORY_SCOPE_AGENT);
        }
    }
}

// ---------------- launch ----------------

extern "C" void kernel_launch(void* const* d_in, const int* in_sizes, int n_in,
                              void* d_out, int out_size, void* d_ws, size_t ws_size,
                              hipStream_t stream) {
    const int*   x_ids = (const int*)d_in[0];
    const int*   ei    = (const int*)d_in[1];
    const float* emb   = (const float*)d_in[3];
    const float* W1    = (const float*)d_in[4];
    const float* as1w  = (const float*)d_in[5];
    const float* ad1w  = (const float*)d_in[6];
    const float* b1    = (const float*)d_in[7];
    const float* W2    = (const float*)d_in[8];
    const float* as2w  = (const float*)d_in[9];
    const float* ad2w  = (const float*)d_in[10];
    const float* b2    = (const float*)d_in[11];
    const float* Wih   = (const float*)d_in[12];
    const float* Whh   = (const float*)d_in[13];
    const float* bih   = (const float*)d_in[14];
    const float* bhh   = (const float*)d_in[15];
    const float* Wp    = (const float*)d_in[16];
    const float* bp    = (const float*)d_in[17];

    char* ws = (char*)d_ws;
    size_t off = 0;
    auto alloc = [&](size_t bytes) -> void* {
        void* p = ws + off;
        off += (bytes + 255) & ~(size_t)255;
        return p;
    };
    // U: union of aggxb (8 x NN x 256 bf16 = 64MiB, dead after k_gemm_b8) and
    //    Xg (NN x 1024 f32 = 64MiB, written later by the Xg GEMM)
    unsigned short* U     = (unsigned short*)alloc((size_t)8 * NN * 256 * 2);
    unsigned short* aggxb = U;
    float*          Xg    = (float*)U;
    unsigned short* out1b = (unsigned short*)alloc((size_t)NN * 2048 * 2);  // reused as hX
    unsigned short* hX    = out1b;   // h ring [64][256][256] bf16 (out1b dead by LSTM time)
    unsigned short* xb    = (unsigned short*)alloc((size_t)NN * 256 * 2);
    unsigned short* x2b   = (unsigned short*)alloc((size_t)NN * 256 * 2);
    unsigned short* out2b = (unsigned short*)alloc((size_t)NN * 256 * 2);
    unsigned short* W1t   = (unsigned short*)alloc((size_t)2048 * 256 * 2);
    unsigned short* W2t   = (unsigned short*)alloc((size_t)256 * 2048 * 2);
    unsigned short* Wihb  = (unsigned short*)alloc((size_t)1024 * 256 * 2);
    unsigned short* Whhb  = (unsigned short*)alloc((size_t)1024 * 256 * 2);
    unsigned short* WhhR  = (unsigned short*)alloc((size_t)1024 * 256 * 2);
    unsigned short* Wpb   = (unsigned short*)alloc((size_t)37000 * 256 * 2);
    unsigned short* Vb    = (unsigned short*)alloc((size_t)16 * 256 * 2);
    float*          bb    = (float*)alloc(1024 * 4);
    float*          D     = (float*)alloc((size_t)NN * 16 * 4);   // als1|ald1 packed
    float*          als2  = (float*)alloc((size_t)NN * 4);
    float*          ald2  = (float*)alloc((size_t)NN * 4);
    unsigned short* hTb   = (unsigned short*)alloc((size_t)256 * 256 * 2);
    int* deg       = (int*)alloc((size_t)NN * 4);
    int* row_start = (int*)alloc((size_t)(NN + 1) * 4);
    int* cursor    = (int*)alloc((size_t)NN * 4);
    int* csr_src   = (int*)alloc((size_t)NTOT * 4);
    int* flags     = (int*)alloc((size_t)16 * 64 * 4);   // per (group, step) counters
    (void)ws_size; (void)in_sizes; (void)n_in; (void)out_size; (void)hTb;

    // weight prep
    k_transpose_bf16<<<dim3(2048 / 32, 256 / 32), dim3(32, 8), 0, stream>>>(W1, W1t, 256, 2048);
    k_transpose_bf16<<<dim3(256 / 32, 2048 / 32), dim3(32, 8), 0, stream>>>(W2, W2t, 2048, 256);
    k_cast_bf16<<<(262144 / 4 + 255) / 256, 256, 0, stream>>>(Wih, Wihb, 262144 / 4);
    k_cast_bf16<<<(262144 / 4 + 255) / 256, 256, 0, stream>>>(Whh, Whhb, 262144 / 4);
    k_cast_bf16<<<(9472000 / 4 + 255) / 256, 256, 0, stream>>>(Wp, Wpb, 9472000 / 4);
    k_add2<<<4, 256, 0, stream>>>(bih, bhh, bb, 1024);
    k_repack_whh<<<32768 / 256, 256, 0, stream>>>(Whhb, WhhR);
    k_zero<<<4, 256, 0, stream>>>(flags, 1024);
    k_build_v<<<16, 256, 0, stream>>>(W1, as1w, ad1w, Vb);

    // CSR
    k_deg_init<<<NN / 256, 256, 0, stream>>>(deg);
    k_deg_count<<<NE / 256, 256, 0, stream>>>(ei, deg);
    k_scan<<<1, 1024, 0, stream>>>(deg, row_start, cursor);
    k_fill<<<(NTOT + 255) / 256, 256, 0, stream>>>(ei, cursor, csr_src);

    // embedding gather
    k_gather_x<<<NN * 64 / 256, 256, 0, stream>>>(x_ids, emb, xb);

    // GAT layer 1 (restructured: dots from x, aggregate x, then per-head projection)
    k_gemm_bt<false, false><<<dim3(NN / 128, 1), 256, 0, stream>>>(
        xb, Vb, D, nullptr, NN, 16, 256);
    k_aggx<<<NN, 256, 0, stream>>>(row_start, csr_src, D, xb, aggxb);
    k_gemm_b8<<<dim3(NN / 128, 2, 8), 256, 0, stream>>>(aggxb, W1t, out1b, b1);

    // GAT layer 2
    k_gemm_bt<true, false><<<dim3(NN / 128, 256 / 128), 256, 0, stream>>>(
        out1b, W2t, x2b, nullptr, NN, 256, 2048);
    k_alpha2<<<NN, 64, 0, stream>>>(x2b, as2w, ad2w, als2, ald2);
    k_agg2<<<NN, 64, 0, stream>>>(row_start, csr_src, als2, ald2, x2b, b2, out2b);

    // LSTM: Xg = out2 @ Wih^T + (bih + bhh)  (into U; aggxb dead after k_gemm_b8)
    k_gemm_bt<false, true><<<dim3(NN / 128, 1024 / 128), 256, 0, stream>>>(
        out2b, Wihb, Xg, bb, NN, 1024, 256);
    k_lstm8<<<64, 256, 0, stream>>>(Xg, WhhR, hX, flags);

    // final projection: A = h at t=63, laid out [256][256] bf16 row-major
    k_gemm_bt<false, true><<<dim3(256 / 128, (37000 + 127) / 128), 256, 0, stream>>>(
        hX + (size_t)63 * 256 * 256, Wpb, (float*)d_out, bp, 256, 37000, 256);
}

// Round 9
// 608.454 us; speedup vs baseline: 1.2986x; 1.0163x over previous
//
#include <hip/hip_runtime.h>
#include <hip/hip_bf16.h>
#include <cstdint>

#define HD 256
#define NHEADS 8
#define NB 256
#define SL 64
#define NN 16384
#define NE 131072
#define NTOT (NE + NN)   // 147456

typedef float floatx4 __attribute__((ext_vector_type(4)));
typedef short shortx8 __attribute__((ext_vector_type(8)));
typedef unsigned short ushortx8 __attribute__((ext_vector_type(8)));
typedef unsigned short ushortx4 __attribute__((ext_vector_type(4)));
typedef unsigned uintx2 __attribute__((ext_vector_type(2)));

__device__ __forceinline__ unsigned short f2bf(float f) {
    union { float f; unsigned u; } a; a.f = f;
    unsigned r = a.u + 0x7fffu + ((a.u >> 16) & 1u);
    return (unsigned short)(r >> 16);
}
__device__ __forceinline__ float bf2f(unsigned short b) {
    union { unsigned u; float f; } a; a.u = ((unsigned)b) << 16;
    return a.f;
}

// system-coherent (write-through / L2-bypass) accessors for cross-block h exchange.
// sc0 sc1 => the access happens at the coherence point (L3/IC); L2 is never dirty
// and never serves stale lines, so no buffer_wbl2/buffer_inv walks are needed.
// (v7 measured those walks at 13.6k cy/step; v8's sc protocol = 7.8k cy/step.)
__device__ __forceinline__ void store_b64_sys(unsigned short* p, uintx2 v) {
    asm volatile("global_store_dwordx2 %0, %1, off sc0 sc1" :: "v"(p), "v"(v) : "memory");
}
__device__ __forceinline__ shortx8 load_b128_sys(const unsigned short* p) {
    shortx8 r;
    asm volatile("global_load_dwordx4 %0, %1, off sc0 sc1" : "=v"(r) : "v"(p) : "memory");
    return r;
}
__device__ __forceinline__ unsigned load_b32_sys(const int* p) {
    unsigned r;
    asm volatile("global_load_dword %0, %1, off sc0 sc1" : "=v"(r) : "v"(p) : "memory");
    asm volatile("s_waitcnt vmcnt(0)" ::: "memory");
    return r;
}

// ---------------- conversions ----------------

__global__ void k_cast_bf16(const float* __restrict__ in, unsigned short* __restrict__ out, int n4) {
    int i = blockIdx.x * 256 + threadIdx.x;
    if (i >= n4) return;
    float4 v = ((const float4*)in)[i];
    ushortx4 o;
    o[0] = f2bf(v.x); o[1] = f2bf(v.y); o[2] = f2bf(v.z); o[3] = f2bf(v.w);
    *(ushortx4*)&out[i * 4] = o;
}

// out[n][k] = bf16(in[k][n]); in is K x N fp32. grid (N/32, K/32), block (32,8)
__global__ void k_transpose_bf16(const float* __restrict__ in, unsigned short* __restrict__ out,
                                 int K, int N) {
    __shared__ float t[32][33];
    int nb = blockIdx.x * 32, kb = blockIdx.y * 32;
    int tx = threadIdx.x, ty = threadIdx.y;
#pragma unroll
    for (int i = 0; i < 4; ++i) {
        int k = kb + ty + i * 8;
        t[ty + i * 8][tx] = in[(size_t)k * N + nb + tx];
    }
    __syncthreads();
#pragma unroll
    for (int i = 0; i < 4; ++i) {
        int nrow = nb + ty + i * 8;
        out[(size_t)nrow * K + kb + tx] = f2bf(t[tx][ty + i * 8]);
    }
}

__global__ void k_add2(const float* __restrict__ a, const float* __restrict__ b,
                       float* __restrict__ o, int n) {
    int i = blockIdx.x * 256 + threadIdx.x;
    if (i < n) o[i] = a[i] + b[i];
}

__global__ void k_zero(int* __restrict__ p, int n) {
    int i = blockIdx.x * 256 + threadIdx.x;
    if (i < n) p[i] = 0;
}

// x_b[n][d] = bf16(emb[x_ids[n]][d]), row 0 of emb forced to 0
__global__ void k_gather_x(const int* __restrict__ ids, const float* __restrict__ emb,
                           unsigned short* __restrict__ xb) {
    int i = blockIdx.x * 256 + threadIdx.x;   // over NN*64
    int n = i >> 6, d4 = (i & 63) << 2;
    int id = ids[n];
    float4 v = make_float4(0.f, 0.f, 0.f, 0.f);
    if (id != 0) v = *(const float4*)&emb[(size_t)id * HD + d4];
    ushortx4 o;
    o[0] = f2bf(v.x); o[1] = f2bf(v.y); o[2] = f2bf(v.z); o[3] = f2bf(v.w);
    *(ushortx4*)&xb[(size_t)n * HD + d4] = o;
}

// ---------------- GEMM: C(MxN) = A(MxK bf16) * B^T  (B given as N x K bf16) ----------------

template <bool OUT_BF16, bool HAS_BIAS>
__global__ __launch_bounds__(256, 2) void k_gemm_bt(
    const unsigned short* __restrict__ A, const unsigned short* __restrict__ B,
    void* __restrict__ C, const float* __restrict__ bias, int M, int Nn, int K) {
    constexpr int LDT = 56;
    __shared__ unsigned short As[128 * LDT];
    __shared__ unsigned short Bs[128 * LDT];
    int tid = threadIdx.x;
    int wave = tid >> 6, lane = tid & 63;
    int q = lane >> 4, c16 = lane & 15;
    long m0 = (long)blockIdx.x * 128;
    long n0 = (long)blockIdx.y * 128;
    int wm = (wave & 1) << 6, wn = (wave >> 1) << 6;
    floatx4 acc[4][4] = {};
    int lrow = tid >> 2;
    int lk = (tid & 3) << 3;
    const unsigned short* Arow0 = A + (m0 + lrow) * K + lk;
    const unsigned short* Arow1 = A + (m0 + 64 + lrow) * K + lk;
    long nb0 = n0 + lrow;      if (nb0 >= Nn) nb0 = Nn - 1;
    long nb1 = n0 + 64 + lrow; if (nb1 >= Nn) nb1 = Nn - 1;
    const unsigned short* Brow0 = B + nb0 * K + lk;
    const unsigned short* Brow1 = B + nb1 * K + lk;

    for (int k0 = 0; k0 < K; k0 += 32) {
        ushortx8 a0 = *(const ushortx8*)(Arow0 + k0);
        ushortx8 a1 = *(const ushortx8*)(Arow1 + k0);
        ushortx8 b0 = *(const ushortx8*)(Brow0 + k0);
        ushortx8 b1 = *(const ushortx8*)(Brow1 + k0);
        __syncthreads();
        *(ushortx8*)&As[lrow * LDT + lk] = a0;
        *(ushortx8*)&As[(64 + lrow) * LDT + lk] = a1;
        *(ushortx8*)&Bs[lrow * LDT + lk] = b0;
        *(ushortx8*)&Bs[(64 + lrow) * LDT + lk] = b1;
        __syncthreads();
        shortx8 af[4], bfr[4];
#pragma unroll
        for (int mt = 0; mt < 4; ++mt)
            af[mt] = *(const shortx8*)&As[(wm + mt * 16 + c16) * LDT + q * 8];
#pragma unroll
        for (int nt = 0; nt < 4; ++nt)
            bfr[nt] = *(const shortx8*)&Bs[(wn + nt * 16 + c16) * LDT + q * 8];
#pragma unroll
        for (int mt = 0; mt < 4; ++mt)
#pragma unroll
            for (int nt = 0; nt < 4; ++nt)
                acc[mt][nt] = __builtin_amdgcn_mfma_f32_16x16x32_bf16(af[mt], bfr[nt], acc[mt][nt], 0, 0, 0);
    }
#pragma unroll
    for (int mt = 0; mt < 4; ++mt) {
        long row_base = m0 + wm + mt * 16 + q * 4;
#pragma unroll
        for (int nt = 0; nt < 4; ++nt) {
            long col = n0 + wn + nt * 16 + c16;
            if (col >= Nn) continue;
            float bv = HAS_BIAS ? bias[col] : 0.0f;
#pragma unroll
            for (int r = 0; r < 4; ++r) {
                float v = acc[mt][nt][r] + bv;
                long idx = (row_base + r) * (long)Nn + col;
                if (OUT_BF16) ((unsigned short*)C)[idx] = f2bf(v);
                else          ((float*)C)[idx] = v;
            }
        }
    }
}

// ---------------- batched per-head GEMM: out1[n][hh*256+j] = ELU(aggx[hh] @ W1_hh + b1) ----
__global__ __launch_bounds__(256, 2) void k_gemm_b8(
    const unsigned short* __restrict__ Ab, const unsigned short* __restrict__ W1t,
    unsigned short* __restrict__ C, const float* __restrict__ b1) {
    constexpr int LDT = 56;
    __shared__ unsigned short As[128 * LDT];
    __shared__ unsigned short Bs[128 * LDT];
    int tid = threadIdx.x;
    int wave = tid >> 6, lane = tid & 63;
    int q = lane >> 4, c16 = lane & 15;
    int hh = blockIdx.z;
    const unsigned short* A = Ab + (size_t)hh * NN * 256;
    const unsigned short* B = W1t + (size_t)hh * 256 * 256;
    long m0 = (long)blockIdx.x * 128;
    long n0 = (long)blockIdx.y * 128;   // within head (Nn = 256)
    int wm = (wave & 1) << 6, wn = (wave >> 1) << 6;
    floatx4 acc[4][4] = {};
    int lrow = tid >> 2;
    int lk = (tid & 3) << 3;
    const unsigned short* Arow0 = A + (m0 + lrow) * 256 + lk;
    const unsigned short* Arow1 = A + (m0 + 64 + lrow) * 256 + lk;
    const unsigned short* Brow0 = B + (n0 + lrow) * 256 + lk;
    const unsigned short* Brow1 = B + (n0 + 64 + lrow) * 256 + lk;

    for (int k0 = 0; k0 < 256; k0 += 32) {
        ushortx8 a0 = *(const ushortx8*)(Arow0 + k0);
        ushortx8 a1 = *(const ushortx8*)(Arow1 + k0);
        ushortx8 b0 = *(const ushortx8*)(Brow0 + k0);
        ushortx8 b1 = *(const ushortx8*)(Brow1 + k0);
        __syncthreads();
        *(ushortx8*)&As[lrow * LDT + lk] = a0;
        *(ushortx8*)&As[(64 + lrow) * LDT + lk] = a1;
        *(ushortx8*)&Bs[lrow * LDT + lk] = b0;
        *(ushortx8*)&Bs[(64 + lrow) * LDT + lk] = b1;
        __syncthreads();
        shortx8 af[4], bfr[4];
#pragma unroll
        for (int mt = 0; mt < 4; ++mt)
            af[mt] = *(const shortx8*)&As[(wm + mt * 16 + c16) * LDT + q * 8];
#pragma unroll
        for (int nt = 0; nt < 4; ++nt)
            bfr[nt] = *(const shortx8*)&Bs[(wn + nt * 16 + c16) * LDT + q * 8];
#pragma unroll
        for (int mt = 0; mt < 4; ++mt)
#pragma unroll
            for (int nt = 0; nt < 4; ++nt)
                acc[mt][nt] = __builtin_amdgcn_mfma_f32_16x16x32_bf16(af[mt], bfr[nt], acc[mt][nt], 0, 0, 0);
    }
#pragma unroll
    for (int mt = 0; mt < 4; ++mt) {
        long row_base = m0 + wm + mt * 16 + q * 4;
#pragma unroll
        for (int nt = 0; nt < 4; ++nt) {
            int gcol = hh * 256 + (int)(n0 + wn + nt * 16 + c16);
            float bv = b1[gcol];
#pragma unroll
            for (int r = 0; r < 4; ++r) {
                float v = acc[mt][nt][r] + bv;
                v = v > 0.f ? v : expm1f(v);   // ELU fused (layer-1 activation)
                C[(row_base + r) * 2048 + gcol] = f2bf(v);
            }
        }
    }
}

// ---------------- layer-1 attention-vector build ----------------
// Vb[o][k] = sum_d W1[k][hh*256+d] * a[hh][d]   (o<8: att_src1, hh=o; o>=8: att_dst1, hh=o-8)
__global__ void k_build_v(const float* __restrict__ W1, const float* __restrict__ as1,
                          const float* __restrict__ ad1, unsigned short* __restrict__ Vb) {
    __shared__ float av[256];
    int o = blockIdx.x, k = threadIdx.x;
    int hh = o & 7;
    const float* a = (o < 8) ? as1 : ad1;
    av[k] = a[hh * 256 + k];
    __syncthreads();
    const float* wrow = W1 + (size_t)k * 2048 + hh * 256;
    float sum = 0.f;
#pragma unroll 8
    for (int d = 0; d < 256; ++d) sum += wrow[d] * av[d];
    Vb[o * 256 + k] = f2bf(sum);
}

// ---------------- attention dots (layer 2) ----------------

__global__ void k_alpha2(const unsigned short* __restrict__ x2b, const float* __restrict__ asrc,
                         const float* __restrict__ adst, float* __restrict__ als,
                         float* __restrict__ ald) {
    int n = blockIdx.x, t = threadIdx.x;
    ushortx4 hv = *(const ushortx4*)&x2b[(size_t)n * 256 + t * 4];
    float s = 0.f, d = 0.f;
#pragma unroll
    for (int j = 0; j < 4; ++j) {
        float f = bf2f(hv[j]);
        s += f * asrc[t * 4 + j];
        d += f * adst[t * 4 + j];
    }
    for (int o = 32; o; o >>= 1) { s += __shfl_down(s, o, 64); d += __shfl_down(d, o, 64); }
    if (t == 0) { als[n] = s; ald[n] = d; }
}

// ---------------- CSR build ----------------

__global__ void k_deg_init(int* __restrict__ deg) {
    int i = blockIdx.x * 256 + threadIdx.x;
    if (i < NN) deg[i] = 1;
}
__global__ void k_deg_count(const int* __restrict__ ei, int* __restrict__ deg) {
    int e = blockIdx.x * 256 + threadIdx.x;
    if (e < NE) atomicAdd(&deg[ei[NE + e]], 1);
}
__global__ void k_scan(const int* __restrict__ deg, int* __restrict__ row_start,
                       int* __restrict__ cursor) {
    __shared__ int s[1024];
    int t = threadIdx.x;
    int base = t * 16;
    int loc[16]; int sum = 0;
#pragma unroll
    for (int i = 0; i < 16; ++i) { loc[i] = deg[base + i]; sum += loc[i]; }
    s[t] = sum;
    __syncthreads();
    for (int o = 1; o < 1024; o <<= 1) {
        int v = (t >= o) ? s[t - o] : 0;
        __syncthreads();
        s[t] += v;
        __syncthreads();
    }
    int ex = s[t] - sum;
#pragma unroll
    for (int i = 0; i < 16; ++i) {
        row_start[base + i] = ex;
        cursor[base + i] = ex;
        ex += loc[i];
    }
    if (t == 0) row_start[NN] = NTOT;
}
__global__ void k_fill(const int* __restrict__ ei, int* __restrict__ cursor,
                       int* __restrict__ csr_src) {
    int e = blockIdx.x * 256 + threadIdx.x;
    if (e >= NTOT) return;
    int s, d;
    if (e < NE) { s = ei[e]; d = ei[NE + e]; }
    else        { s = e - NE; d = s; }
    int p = atomicAdd(&cursor[d], 1);
    csr_src[p] = s;
}

// ---------------- GAT layer-1 aggregation over x (256-wide, pre-projection) ----------------
// aggx[hh][n][:] = sum_src alpha[hh,src->n] * x[src][:]  ((sum a x) W1 == sum a (x W1)).
__global__ __launch_bounds__(256) void k_aggx(
    const int* __restrict__ row_start, const int* __restrict__ csr_src,
    const float* __restrict__ D, const unsigned short* __restrict__ xb,
    unsigned short* __restrict__ aggxb) {
    int n = blockIdx.x, t = threadIdx.x;
    int rs = row_start[n];
    int deg = row_start[n + 1] - rs;
    __shared__ float sad[8], sm[8], sinvz[8];
    __shared__ int sed[32];
    __shared__ float wlds[32][8];
    if (t < 8) sad[t] = D[n * 16 + 8 + t];
    __syncthreads();
    int hh = t >> 5, ii = t & 31;
    float adh = sad[hh];
    float lm = -1e30f;
    for (int i = ii; i < deg; i += 32) {
        int s = csr_src[rs + i];
        float e = D[s * 16 + hh] + adh;
        e = e >= 0.f ? e : 0.2f * e;
        lm = fmaxf(lm, e);
    }
    for (int o = 16; o; o >>= 1) lm = fmaxf(lm, __shfl_down(lm, o, 32));
    if (ii == 0) sm[hh] = lm;
    __syncthreads();
    float mh = sm[hh];
    float lz = 0.f;
    for (int i = ii; i < deg; i += 32) {
        int s = csr_src[rs + i];
        float e = D[s * 16 + hh] + adh;
        e = e >= 0.f ? e : 0.2f * e;
        lz += expf(e - mh);
    }
    for (int o = 16; o; o >>= 1) lz += __shfl_down(lz, o, 32);
    if (ii == 0) sinvz[hh] = 1.0f / (lz + 1e-16f);
    __syncthreads();

    float acc[8] = {0.f, 0.f, 0.f, 0.f, 0.f, 0.f, 0.f, 0.f};
    int eh = t & 7, ee = t >> 3;           // weight phase: 32 edges x 8 heads
    for (int base = 0; base < deg; base += 32) {
        int cnt = min(32, deg - base);
        if (t < 32) sed[t] = (t < cnt) ? csr_src[rs + base + t] : 0;
        __syncthreads();
        if (ee < cnt) {
            int s = sed[ee];
            float e = D[s * 16 + eh] + sad[eh];
            e = e >= 0.f ? e : 0.2f * e;
            wlds[ee][eh] = expf(e - sm[eh]) * sinvz[eh];
        }
        __syncthreads();
        for (int e = 0; e < cnt; ++e) {
            float xv = bf2f(xb[(size_t)sed[e] * 256 + t]);
#pragma unroll
            for (int h = 0; h < 8; ++h) acc[h] += wlds[e][h] * xv;
        }
        __syncthreads();
    }
#pragma unroll
    for (int h = 0; h < 8; ++h)
        aggxb[((size_t)h * NN + n) * 256 + t] = f2bf(acc[h]);
}

// ---------------- GAT layer-2 aggregation ----------------

__global__ void k_agg2(const int* __restrict__ row_start, const int* __restrict__ csr_src,
                       const float* __restrict__ als, const float* __restrict__ ald,
                       const unsigned short* __restrict__ x2b, const float* __restrict__ b2,
                       unsigned short* __restrict__ out2b) {
    int n = blockIdx.x, t = threadIdx.x;
    int rs = row_start[n];
    int deg = row_start[n + 1] - rs;
    float adn = ald[n];
    float lm = -1e30f;
    for (int i = t; i < deg; i += 64) {
        float e = als[csr_src[rs + i]] + adn;
        e = e >= 0.f ? e : 0.2f * e;
        lm = fmaxf(lm, e);
    }
    for (int o = 32; o; o >>= 1) lm = fmaxf(lm, __shfl_down(lm, o, 64));
    float mh = __shfl(lm, 0, 64);
    float lz = 0.f;
    for (int i = t; i < deg; i += 64) {
        float e = als[csr_src[rs + i]] + adn;
        e = e >= 0.f ? e : 0.2f * e;
        lz += expf(e - mh);
    }
    for (int o = 32; o; o >>= 1) lz += __shfl_down(lz, o, 64);
    float zz = __shfl(lz, 0, 64);
    float inv_z = 1.0f / (zz + 1e-16f);
    float acc[4] = {0.f, 0.f, 0.f, 0.f};
    for (int i = 0; i < deg; ++i) {
        int s = csr_src[rs + i];
        float e = als[s] + adn;
        e = e >= 0.f ? e : 0.2f * e;
        float w = expf(e - mh) * inv_z;
        ushortx4 hv = *(const ushortx4*)&x2b[(size_t)s * 256 + t * 4];
#pragma unroll
        for (int j = 0; j < 4; ++j) acc[j] += w * bf2f(hv[j]);
    }
    ushortx4 o4;
#pragma unroll
    for (int j = 0; j < 4; ++j) o4[j] = f2bf(acc[j] + b2[t * 4 + j]);
    *(ushortx4*)&out2b[(size_t)n * 256 + t * 4] = o4;
}

// ---------------- LSTM weight repack ----------------
__global__ void k_repack_whh(const unsigned short* __restrict__ Whhb,
                             unsigned short* __restrict__ WhhR) {
    int i = blockIdx.x * 256 + threadIdx.x;    // 32768 threads = 512 frags x 64 lanes
    int lane = i & 63;
    int fi = i >> 6;                            // 0..511
    int f = fi & 3, k0 = (fi >> 2) & 7, w = (fi >> 5) & 3, s = fi >> 7;
    int q = lane >> 4, c16 = lane & 15;
    int gcol = f * 256 + s * 64 + w * 16 + c16;
    int k = k0 * 32 + q * 8;
    ushortx8 v = *(const ushortx8*)&Whhb[(size_t)gcol * 256 + k];
    *(ushortx8*)&WhhR[(size_t)fi * 512 + lane * 8] = v;
}

// ---------------- LSTM recurrence, v10: v8 + coalesced publish + per-wave flags ----------
// v8 (202us = 7.6k cy/step) had three data-movement inefficiencies on the critical
// path: (1) h published as 1024 scattered 2B sc1 stores (16x 32B segments per wave
// inst at the L3 write path); (2) two block barriers + tid0 gating around the
// publish/poll; (3) RMW-polling (serializing atomic at the L3 bank) + s_sleep
// quantization. v10 (gate arithmetic untouched):
//  - h slice staged through 2KB LDS, stored as coalesced dwordx2 sc0 sc1
//    (4 rows x 128B contiguous per wave; 1 store/thread),
//  - per-WAVE publish: each wave drains its own vmcnt then lane0 RMW-adds;
//    flag counts to 16 (4 blocks x 4 waves); no producer barrier,
//  - per-WAVE poll via plain sc0 sc1 LOAD (reads L3 = where the RMW lives;
//    the same freshness v8's h loads proved), no sleep, no consumer barrier.
// Ordering: a wave's next-step LDS stage-write is gated by poll success, which
// requires all 16 publishes, each of which follows that wave's stage-read.
// Bounded spin retained (stall -> wrong data + counters, not a hang).

__global__ __launch_bounds__(256, 1) void k_lstm10(
    const float* __restrict__ Xg, const unsigned short* __restrict__ WhhR,
    unsigned short* __restrict__ hX, int* __restrict__ flags) {
    __shared__ unsigned short wlds[4 * 32 * 512];   // 128KB: [wave][k0*4+f][lane*8]
    __shared__ unsigned short hstage[16 * 68];      // 2.1KB h staging, row stride 68

    int tid = threadIdx.x;
    int w = tid >> 6, lane = tid & 63;
    int q = lane >> 4, c16 = lane & 15;
    int g = blockIdx.x & 15, s = blockIdx.x >> 4;
    int scol = s * 64 + w * 16 + c16;               // h-col this lane owns
    const int fbase = g * 64;

    // one-time preload of this wave's 32 weight frags (32KB) into LDS
    // (no barrier needed: each wave reads back only its own frags)
    const unsigned short* wsrc = WhhR + (size_t)((s * 4 + w) * 32) * 512 + lane * 8;
#pragma unroll
    for (int fi = 0; fi < 32; ++fi)
        *(shortx8*)&wlds[(w * 32 + fi) * 512 + lane * 8] =
            *(const shortx8*)(wsrc + fi * 512);

    float cst[4] = {0.f, 0.f, 0.f, 0.f};
    int srow = tid >> 4, scol4 = (tid & 15) * 4;    // coalesced-store assignment

    for (int t = 0; t < SL; ++t) {
        // Xg prefetch: issued before the poll so HBM latency hides under the wait
        float xg[4][4];
#pragma unroll
        for (int r = 0; r < 4; ++r) {
            const float* xp = Xg + ((size_t)(g * 16 + q * 4 + r) * SL + t) * 1024 + scol;
#pragma unroll
            for (int f = 0; f < 4; ++f) xg[r][f] = xp[f * 256];
        }

        floatx4 acc[4] = {};
        if (t > 0) {
            // per-wave poll: sc load of the 16-count flag (no RMW, no sleep, no barrier)
            int spins = 0;
            while (load_b32_sys(&flags[fbase + t - 1]) < 16u) {
                if (++spins > 30000) break;   // stall -> wrong data, not a hang
            }

            // A-frags: h[t-1], rows g*16+c16 (own batch rows), all 256 h-cols (L3 direct)
            const unsigned short* hp =
                hX + ((size_t)(t - 1) * 256 + g * 16 + c16) * 256 + q * 8;
            shortx8 af[8];
#pragma unroll
            for (int k0 = 0; k0 < 8; ++k0) af[k0] = load_b128_sys(hp + k0 * 32);
            asm volatile("s_waitcnt vmcnt(0)" ::: "memory");
            __builtin_amdgcn_sched_barrier(0);
#pragma unroll
            for (int k0 = 0; k0 < 8; ++k0)
#pragma unroll
                for (int f = 0; f < 4; ++f) {
                    shortx8 b = *(const shortx8*)&wlds[(w * 32 + k0 * 4 + f) * 512 + lane * 8];
                    acc[f] = __builtin_amdgcn_mfma_f32_16x16x32_bf16(af[k0], b, acc[f], 0, 0, 0);
                }
        }

        // epilogue: gates -> c,h; stage h into LDS for coalesced publish
#pragma unroll
        for (int r = 0; r < 4; ++r) {
            float gi = acc[0][r] + xg[r][0];
            float gf = acc[1][r] + xg[r][1];
            float gG = acc[2][r] + xg[r][2];
            float go = acc[3][r] + xg[r][3];
            float si = __builtin_amdgcn_rcpf(1.f + __expf(-gi));
            float sf = __builtin_amdgcn_rcpf(1.f + __expf(-gf));
            float so = __builtin_amdgcn_rcpf(1.f + __expf(-go));
            float tg = 1.f - 2.f * __builtin_amdgcn_rcpf(1.f + __expf(2.f * gG));
            float c = sf * cst[r] + si * tg;
            cst[r] = c;
            float tc = 1.f - 2.f * __builtin_amdgcn_rcpf(1.f + __expf(2.f * c));
            hstage[(q * 4 + r) * 68 + w * 16 + c16] = f2bf(so * tc);
        }
        __syncthreads();   // stage complete (also orders hstage reuse across steps)

        // coalesced write-through publish: row srow, 4 cols from scol4 (8B/thread)
        uintx2 v2 = *(const uintx2*)&hstage[srow * 68 + scol4];
        store_b64_sys(hX + ((size_t)t * 256 + g * 16 + srow) * 256 + s * 64 + scol4, v2);
        asm volatile("s_waitcnt vmcnt(0)" ::: "memory");
        if (t < SL - 1 && lane == 0)
            __hip_atomic_fetch_add(&flags[fbase + t], 1, __ATOMIC_RELAXED,
                                   __HIP_MEMORY_SCOPE_AGENT);   // per-wave publish (16 total)
    }
}

// ---------------- launch ----------------

extern "C" void kernel_launch(void* const* d_in, const int* in_sizes, int n_in,
                              void* d_out, int out_size, void* d_ws, size_t ws_size,
                              hipStream_t stream) {
    const int*   x_ids = (const int*)d_in[0];
    const int*   ei    = (const int*)d_in[1];
    const float* emb   = (const float*)d_in[3];
    const float* W1    = (const float*)d_in[4];
    const float* as1w  = (const float*)d_in[5];
    const float* ad1w  = (const float*)d_in[6];
    const float* b1    = (const float*)d_in[7];
    const float* W2    = (const float*)d_in[8];
    const float* as2w  = (const float*)d_in[9];
    const float* ad2w  = (const float*)d_in[10];
    const float* b2    = (const float*)d_in[11];
    const float* Wih   = (const float*)d_in[12];
    const float* Whh   = (const float*)d_in[13];
    const float* bih   = (const float*)d_in[14];
    const float* bhh   = (const float*)d_in[15];
    const float* Wp    = (const float*)d_in[16];
    const float* bp    = (const float*)d_in[17];

    char* ws = (char*)d_ws;
    size_t off = 0;
    auto alloc = [&](size_t bytes) -> void* {
        void* p = ws + off;
        off += (bytes + 255) & ~(size_t)255;
        return p;
    };
    // U: union of aggxb (8 x NN x 256 bf16 = 64MiB, dead after k_gemm_b8) and
    //    Xg (NN x 1024 f32 = 64MiB, written later by the Xg GEMM)
    unsigned short* U     = (unsigned short*)alloc((size_t)8 * NN * 256 * 2);
    unsigned short* aggxb = U;
    float*          Xg    = (float*)U;
    unsigned short* out1b = (unsigned short*)alloc((size_t)NN * 2048 * 2);  // reused as hX
    unsigned short* hX    = out1b;   // h ring [64][256][256] bf16 (out1b dead by LSTM time)
    unsigned short* xb    = (unsigned short*)alloc((size_t)NN * 256 * 2);
    unsigned short* x2b   = (unsigned short*)alloc((size_t)NN * 256 * 2);
    unsigned short* out2b = (unsigned short*)alloc((size_t)NN * 256 * 2);
    unsigned short* W1t   = (unsigned short*)alloc((size_t)2048 * 256 * 2);
    unsigned short* W2t   = (unsigned short*)alloc((size_t)256 * 2048 * 2);
    unsigned short* Wihb  = (unsigned short*)alloc((size_t)1024 * 256 * 2);
    unsigned short* Whhb  = (unsigned short*)alloc((size_t)1024 * 256 * 2);
    unsigned short* WhhR  = (unsigned short*)alloc((size_t)1024 * 256 * 2);
    unsigned short* Wpb   = (unsigned short*)alloc((size_t)37000 * 256 * 2);
    unsigned short* Vb    = (unsigned short*)alloc((size_t)16 * 256 * 2);
    float*          bb    = (float*)alloc(1024 * 4);
    float*          D     = (float*)alloc((size_t)NN * 16 * 4);   // als1|ald1 packed
    float*          als2  = (float*)alloc((size_t)NN * 4);
    float*          ald2  = (float*)alloc((size_t)NN * 4);
    int* deg       = (int*)alloc((size_t)NN * 4);
    int* row_start = (int*)alloc((size_t)(NN + 1) * 4);
    int* cursor    = (int*)alloc((size_t)NN * 4);
    int* csr_src   = (int*)alloc((size_t)NTOT * 4);
    int* flags     = (int*)alloc((size_t)16 * 64 * 4);   // per (group, step), counts to 16
    (void)ws_size; (void)in_sizes; (void)n_in; (void)out_size;

    // weight prep
    k_transpose_bf16<<<dim3(2048 / 32, 256 / 32), dim3(32, 8), 0, stream>>>(W1, W1t, 256, 2048);
    k_transpose_bf16<<<dim3(256 / 32, 2048 / 32), dim3(32, 8), 0, stream>>>(W2, W2t, 2048, 256);
    k_cast_bf16<<<(262144 / 4 + 255) / 256, 256, 0, stream>>>(Wih, Wihb, 262144 / 4);
    k_cast_bf16<<<(262144 / 4 + 255) / 256, 256, 0, stream>>>(Whh, Whhb, 262144 / 4);
    k_cast_bf16<<<(9472000 / 4 + 255) / 256, 256, 0, stream>>>(Wp, Wpb, 9472000 / 4);
    k_add2<<<4, 256, 0, stream>>>(bih, bhh, bb, 1024);
    k_repack_whh<<<32768 / 256, 256, 0, stream>>>(Whhb, WhhR);
    k_zero<<<4, 256, 0, stream>>>(flags, 1024);
    k_build_v<<<16, 256, 0, stream>>>(W1, as1w, ad1w, Vb);

    // CSR
    k_deg_init<<<NN / 256, 256, 0, stream>>>(deg);
    k_deg_count<<<NE / 256, 256, 0, stream>>>(ei, deg);
    k_scan<<<1, 1024, 0, stream>>>(deg, row_start, cursor);
    k_fill<<<(NTOT + 255) / 256, 256, 0, stream>>>(ei, cursor, csr_src);

    // embedding gather
    k_gather_x<<<NN * 64 / 256, 256, 0, stream>>>(x_ids, emb, xb);

    // GAT layer 1 (dots from x, aggregate x, per-head projection with fused ELU)
    k_gemm_bt<false, false><<<dim3(NN / 128, 1), 256, 0, stream>>>(
        xb, Vb, D, nullptr, NN, 16, 256);
    k_aggx<<<NN, 256, 0, stream>>>(row_start, csr_src, D, xb, aggxb);
    k_gemm_b8<<<dim3(NN / 128, 2, 8), 256, 0, stream>>>(aggxb, W1t, out1b, b1);

    // GAT layer 2
    k_gemm_bt<true, false><<<dim3(NN / 128, 256 / 128), 256, 0, stream>>>(
        out1b, W2t, x2b, nullptr, NN, 256, 2048);
    k_alpha2<<<NN, 64, 0, stream>>>(x2b, as2w, ad2w, als2, ald2);
    k_agg2<<<NN, 64, 0, stream>>>(row_start, csr_src, als2, ald2, x2b, b2, out2b);

    // LSTM: Xg = out2 @ Wih^T + (bih + bhh)  (into U; aggxb dead after k_gemm_b8)
    k_gemm_bt<false, true><<<dim3(NN / 128, 1024 / 128), 256, 0, stream>>>(
        out2b, Wihb, Xg, bb, NN, 1024, 256);
    k_lstm10<<<64, 256, 0, stream>>>(Xg, WhhR, hX, flags);

    // final projection: A = h at t=63, laid out [256][256] bf16 row-major
    k_gemm_bt<false, true><<<dim3(256 / 128, (37000 + 127) / 128), 256, 0, stream>>>(
        hX + (size_t)63 * 256 * 256, Wpb, (float*)d_out, bp, 256, 37000, 256);
}